// Round 1
// baseline (7816.608 us; speedup 1.0000x reference)
//
#include <hip/hip_runtime.h>
#include <hip/hip_bf16.h>

// Problem: 8 independent LSTMs (HID=512, input_size=1) over T=256 steps, batch 128,
// then out[b,j] = sum_t (sum_n h_n[b,t][511] * x[n,b,t]) * Wl[j,t] + bl[j].
//
// Design (round 1):
//  - grid 256 blocks, 128 threads (2 waves). block -> (branch n = blk&7, 16 hidden
//    cols j0 = (blk>>3)*16, all 4 gate types). Branch-local 32-block barrier per step.
//  - Whh slice (4 types x 16 cols x 512 k) bf16 in LDS (64KB), staged once,
//    XOR-swizzled 16B chunks to keep ds_read_b128 at the conflict-free floor.
//  - gates = h @ Whh^T via mfma_f32_16x16x32_bf16; wave = 64 batch rows (4 m-frags),
//    4 n-tiles = i,f,g,o for the SAME hidden col per lane -> pointwise is lane-local.
//  - cc in VGPRs across all steps; h ping-pongs between two global bf16 buffers.

#define NBR   8
#define BATCH 128
#define HIDN  512
#define TLEN  256

typedef __attribute__((ext_vector_type(8))) short bf16x8;
typedef __attribute__((ext_vector_type(4))) float f32x4;

__device__ __forceinline__ unsigned short bf16_rne(float f) {
  unsigned int u = __float_as_uint(f);
  u += 0x7FFFu + ((u >> 16) & 1u);
  return (unsigned short)(u >> 16);
}

__device__ __forceinline__ float fast_rcp(float x) { return __builtin_amdgcn_rcpf(x); }

__device__ __forceinline__ float sigm(float x) {
  return fast_rcp(1.0f + __expf(-x));
}
__device__ __forceinline__ float tanh_(float x) {
  float ax = fabsf(x);
  float e  = __expf(-2.0f * ax);              // in (0,1]
  float t  = (1.0f - e) * fast_rcp(1.0f + e); // tanh(|x|)
  return copysignf(t, x);
}

__global__ __launch_bounds__(128) void lstm_main(
    const float* __restrict__ c_in,   // (128,256,1)
    const float* __restrict__ Wih,    // (8,2048,1)
    const float* __restrict__ Whh,    // (8,2048,512)
    const float* __restrict__ b_ih,   // (8,2048)
    const float* __restrict__ b_hh,   // (8,2048)
    __hip_bfloat16* __restrict__ h0,  // (8,128,512) bf16 ping
    __hip_bfloat16* __restrict__ h1,  // (8,128,512) bf16 pong
    float* __restrict__ ys,           // (256,8,128)
    unsigned int* __restrict__ bars)  // 8 counters, 64B apart, pre-zeroed
{
  __shared__ uint4 Wlds[4096];  // 64KB: row = tp*16+col (64 rows), 64 chunks of 8 bf16

  const int tid  = threadIdx.x;
  const int lane = tid & 63;
  const int wave = tid >> 6;          // 0..1, 64 batch rows each
  const int n    = blockIdx.x & 7;    // branch (XCD-locality heuristic)
  const int jt   = blockIdx.x >> 3;   // 0..31 hidden-col tile
  const int j0   = jt << 4;
  const int col  = lane & 15;         // hidden col within tile / A-frag row
  const int q    = lane >> 4;         // 0..3
  const int swz  = col & 7;

  // ---- stage Whh slice -> LDS bf16, swizzled ----
  for (int idx = tid; idx < 4096; idx += 128) {
    int row  = idx >> 6;              // tp*16 + wcol
    int kc   = idx & 63;              // 16B chunk (8 k-elements)
    int tp   = row >> 4;
    int wcol = row & 15;
    const float* src = Whh + ((size_t)(n * 2048 + tp * 512 + j0 + wcol) * 512 + kc * 8);
    float4 f0 = *(const float4*)(src);
    float4 f1 = *(const float4*)(src + 4);
    uint4 v;
    v.x = (unsigned)bf16_rne(f0.x) | ((unsigned)bf16_rne(f0.y) << 16);
    v.y = (unsigned)bf16_rne(f0.z) | ((unsigned)bf16_rne(f0.w) << 16);
    v.z = (unsigned)bf16_rne(f1.x) | ((unsigned)bf16_rne(f1.y) << 16);
    v.w = (unsigned)bf16_rne(f1.z) | ((unsigned)bf16_rne(f1.w) << 16);
    Wlds[(row << 6) | (kc ^ (wcol & 7))] = v;
  }

  // per-lane static gate params (depend only on col)
  float wih_g[4], bias_g[4];
#pragma unroll
  for (int tp = 0; tp < 4; ++tp) {
    int g = n * 2048 + tp * 512 + j0 + col;
    wih_g[tp]  = Wih[g];
    bias_g[tp] = b_ih[g] + b_hh[g];
  }

  int brow[4];
#pragma unroll
  for (int nt = 0; nt < 4; ++nt) brow[nt] = (nt * 16 + col) << 6;
  int abase[4];
#pragma unroll
  for (int mt = 0; mt < 4; ++mt)
    abase[mt] = (n * 128 + wave * 64 + mt * 16 + col) * 64 + q;  // uint4 index into h

  float cc[4][4];
#pragma unroll
  for (int a = 0; a < 4; ++a)
#pragma unroll
    for (int b = 0; b < 4; ++b) cc[a][b] = 0.0f;

  __hip_bfloat16* cur = h0;
  __hip_bfloat16* nxt = h1;
  unsigned int* bar = bars + n * 16;

  __syncthreads();

  for (int t = 0; t < TLEN; ++t) {
    f32x4 acc[4][4];
#pragma unroll
    for (int mt = 0; mt < 4; ++mt)
#pragma unroll
      for (int nt = 0; nt < 4; ++nt) acc[mt][nt] = (f32x4){0.f, 0.f, 0.f, 0.f};

    const uint4* curU = (const uint4*)cur;
#pragma unroll 2
    for (int ks = 0; ks < 16; ++ks) {
      bf16x8 af[4], bfr[4];
#pragma unroll
      for (int mt = 0; mt < 4; ++mt)
        af[mt] = __builtin_bit_cast(bf16x8, curU[abase[mt] + 4 * ks]);
#pragma unroll
      for (int nt = 0; nt < 4; ++nt)
        bfr[nt] = __builtin_bit_cast(bf16x8, Wlds[brow[nt] + ((4 * ks + q) ^ swz)]);
#pragma unroll
      for (int mt = 0; mt < 4; ++mt)
#pragma unroll
        for (int nt = 0; nt < 4; ++nt)
          acc[mt][nt] = __builtin_amdgcn_mfma_f32_16x16x32_bf16(af[mt], bfr[nt], acc[mt][nt], 0, 0, 0);
    }

    // ---- pointwise LSTM update (lane-local: nt 0..3 = i,f,g,o at this lane's col) ----
    unsigned short* nxtU = (unsigned short*)nxt;
#pragma unroll
    for (int mt = 0; mt < 4; ++mt) {
      int b0 = wave * 64 + mt * 16 + q * 4;
#pragma unroll
      for (int r = 0; r < 4; ++r) {
        int b = b0 + r;
        float cv = c_in[b * 256 + t];
        float gi = acc[mt][0][r] + wih_g[0] * cv + bias_g[0];
        float gf = acc[mt][1][r] + wih_g[1] * cv + bias_g[1];
        float gg = acc[mt][2][r] + wih_g[2] * cv + bias_g[2];
        float go = acc[mt][3][r] + wih_g[3] * cv + bias_g[3];
        float ncc = sigm(gf) * cc[mt][r] + sigm(gi) * tanh_(gg);
        cc[mt][r] = ncc;
        float hv = sigm(go) * tanh_(ncc);
        nxtU[(n * 128 + b) * 512 + j0 + col] = bf16_rne(hv);
        if (jt == 31 && col == 15)            // hidden feature 511
          ys[t * (NBR * BATCH) + n * BATCH + b] = hv;
      }
    }

    // ---- branch-local barrier (32 blocks), monotonic counter ----
    __threadfence();
    __syncthreads();
    if (tid == 0) {
      __hip_atomic_fetch_add(bar, 1u, __ATOMIC_ACQ_REL, __HIP_MEMORY_SCOPE_AGENT);
      unsigned int tgt = 32u * (unsigned)(t + 1);
      while (__hip_atomic_load(bar, __ATOMIC_ACQUIRE, __HIP_MEMORY_SCOPE_AGENT) < tgt)
        __builtin_amdgcn_s_sleep(1);
    }
    __syncthreads();
    __hip_bfloat16* tsw = cur; cur = nxt; nxt = tsw;
  }
}

// out[b,j] = sum_t (sum_n ys[t,n,b]*x[n,b,t]) * Wl[j,t] + bl[j]
__global__ __launch_bounds__(256) void finalize_k(
    const float* __restrict__ ys, const float* __restrict__ x,
    const float* __restrict__ Wl, const float* __restrict__ bl,
    float* __restrict__ out)
{
  int b = blockIdx.x;
  int tid = threadIdx.x;  // = t
  __shared__ float r[256];
  float acc = 0.f;
#pragma unroll
  for (int n = 0; n < NBR; ++n)
    acc += ys[tid * (NBR * BATCH) + n * BATCH + b] * x[(n * BATCH + b) * 256 + tid];
  r[tid] = acc;
  __syncthreads();
  int wv = tid >> 6, ln = tid & 63;
#pragma unroll
  for (int jj = 0; jj < 2; ++jj) {
    int j = wv * 2 + jj;
    float p = 0.f;
#pragma unroll
    for (int t2 = ln; t2 < 256; t2 += 64) p += r[t2] * Wl[j * 256 + t2];
#pragma unroll
    for (int s = 32; s > 0; s >>= 1) p += __shfl_down(p, s, 64);
    if (ln == 0) out[b * NBR + j] = p + bl[j];
  }
}

extern "C" void kernel_launch(void* const* d_in, const int* in_sizes, int n_in,
                              void* d_out, int out_size, void* d_ws, size_t ws_size,
                              hipStream_t stream) {
  const float* x    = (const float*)d_in[0];
  const float* c    = (const float*)d_in[1];
  const float* Wih  = (const float*)d_in[2];
  const float* Whh  = (const float*)d_in[3];
  const float* b_ih = (const float*)d_in[4];
  const float* b_hh = (const float*)d_in[5];
  // d_in[6] = hn0 (zeros by construction; h buffer is memset to 0)
  const float* Wl   = (const float*)d_in[7];
  const float* bl   = (const float*)d_in[8];
  float* out = (float*)d_out;

  char* ws = (char*)d_ws;
  const size_t HBYTES = (size_t)NBR * BATCH * HIDN * sizeof(__hip_bfloat16);  // 512KB
  __hip_bfloat16* h0 = (__hip_bfloat16*)(ws);
  __hip_bfloat16* h1 = (__hip_bfloat16*)(ws + HBYTES);
  float* ys          = (float*)(ws + 2 * HBYTES);                 // 1MB
  unsigned int* bars = (unsigned int*)(ws + 2 * HBYTES + (size_t)TLEN * NBR * BATCH * 4);

  // ws is re-poisoned (0xAA) before every timed launch: re-init state every call.
  hipMemsetAsync(h0, 0, HBYTES, stream);           // h(t=0) = 0 (== hn0)
  hipMemsetAsync(bars, 0, 8 * 64, stream);         // barrier counters

  lstm_main<<<256, 128, 0, stream>>>(c, Wih, Whh, b_ih, b_hh, h0, h1, ys, bars);
  finalize_k<<<BATCH, 256, 0, stream>>>(ys, x, Wl, bl, out);
}

// Round 2
// 5172.775 us; speedup vs baseline: 1.5111x; 1.5111x over previous
//
#include <hip/hip_runtime.h>
#include <hip/hip_bf16.h>

// 8 independent LSTMs (HID=512, input=1 scalar/step) x T=256, batch 128, then a
// tiny (B,T)x(T->8) projection.
//
// Round 2: kill the L2-flush disease of round 1 (WRITE_SIZE 265MB, 30us/step).
//  - All cross-block writes (h, ys, flags) are RELAXED agent-scope atomic stores
//    -> global_store sc1, write-through to MALL; L2 never gets dirty, so the one
//    release (flag store) per step has nothing to flush.
//  - h loads are normal b128 vector loads; one agent acquire fence per step
//    (buffer_inv) makes them coherent.
//  - Barrier = 32 store-only flag slots per branch; poll = one coalesced 128B
//    relaxed load per wave. No atomic RMW contention.
//  - MFMA operands swapped vs round 1: A = Whh (m=gate rows), B = h (n=batch).
//    C layout row=(lane>>4)*4+reg => each lane holds 4 CONSECUTIVE hidden cols
//    -> h writeback is 2x 8B packed stores per lane.
//  - 256-thr blocks (4 waves): all 4 SIMDs of the CU do MFMA. grid=256, branch
//    n = blk&7, 16 hidden cols (x4 gate types) per block.

#define NBR   8
#define BATCH 128
#define HIDN  512
#define TLEN  256

typedef __attribute__((ext_vector_type(8))) short bf16x8;
typedef __attribute__((ext_vector_type(4))) float f32x4;

__device__ __forceinline__ unsigned short bf16_rne(float f) {
  unsigned int u = __float_as_uint(f);
  u += 0x7FFFu + ((u >> 16) & 1u);
  return (unsigned short)(u >> 16);
}

__device__ __forceinline__ float sigm(float x) {
  return __builtin_amdgcn_rcpf(1.0f + __expf(-x));
}
__device__ __forceinline__ float tanh_(float x) {
  float ax = fabsf(x);
  float e  = __expf(-2.0f * ax);
  float t  = (1.0f - e) * __builtin_amdgcn_rcpf(1.0f + e);
  return copysignf(t, x);
}

__global__ __launch_bounds__(256, 1) void lstm_main(
    const float* __restrict__ c_in,   // (128,256)
    const float* __restrict__ Wih,    // (8,2048)
    const float* __restrict__ Whh,    // (8,2048,512)
    const float* __restrict__ b_ih,   // (8,2048)
    const float* __restrict__ b_hh,   // (8,2048)
    __hip_bfloat16* __restrict__ h0,  // (8,128,512) bf16 ping (pre-zeroed)
    __hip_bfloat16* __restrict__ h1,  // (8,128,512) bf16 pong
    float* __restrict__ ys,           // (256,8,128)
    unsigned int* __restrict__ flags) // 8 branches x 32 slots, pre-zeroed
{
  __shared__ uint4 Wlds[4096];  // 64KB: row = tp*16 + mrow (64 rows) x 64 16B-chunks

  const int tid  = threadIdx.x;
  const int lane = tid & 63;
  const int w    = tid >> 6;          // wave 0..3 -> batches 32w..32w+31
  const int ln15 = lane & 15;
  const int q    = lane >> 4;         // 0..3
  const int n    = blockIdx.x & 7;    // branch
  const int jt   = blockIdx.x >> 3;   // 0..31 (also this block's flag slot)
  const int j0   = jt << 4;
  const int swz  = ln15 & 7;

  // ---- stage Whh slice -> LDS bf16 (once), 16B chunks XOR-swizzled ----
  for (int idx = tid; idx < 4096; idx += 256) {
    int row  = idx >> 6;              // tp*16 + wcol
    int kc   = idx & 63;
    int tp   = row >> 4;
    int wcol = row & 15;
    const float* src = Whh + ((size_t)(n * 2048 + tp * 512 + j0 + wcol) * 512 + kc * 8);
    float4 f0 = *(const float4*)(src);
    float4 f1 = *(const float4*)(src + 4);
    uint4 v;
    v.x = (unsigned)bf16_rne(f0.x) | ((unsigned)bf16_rne(f0.y) << 16);
    v.y = (unsigned)bf16_rne(f0.z) | ((unsigned)bf16_rne(f0.w) << 16);
    v.z = (unsigned)bf16_rne(f1.x) | ((unsigned)bf16_rne(f1.y) << 16);
    v.w = (unsigned)bf16_rne(f1.z) | ((unsigned)bf16_rne(f1.w) << 16);
    Wlds[(row << 6) | (kc ^ (wcol & 7))] = v;
  }

  // per-lane gate constants: type tp, reg r -> hidden col j0 + 4q + r
  float wih_g[4][4], bias_g[4][4];
#pragma unroll
  for (int tp = 0; tp < 4; ++tp)
#pragma unroll
    for (int r = 0; r < 4; ++r) {
      int g = n * 2048 + tp * 512 + j0 + 4 * q + r;
      wih_g[tp][r]  = Wih[g];
      bias_g[tp][r] = b_ih[g] + b_hh[g];
    }

  int bb[2], hb[2];
#pragma unroll
  for (int nt = 0; nt < 2; ++nt) {
    bb[nt] = w * 32 + nt * 16 + ln15;                  // batch
    hb[nt] = (n * 128 + bb[nt]) * 64 + q;              // uint4 idx into h row
  }
  const int wrow[4] = { (0 * 16 + ln15) << 6, (1 * 16 + ln15) << 6,
                        (2 * 16 + ln15) << 6, (3 * 16 + ln15) << 6 };

  float cc[2][4];
#pragma unroll
  for (int a = 0; a < 2; ++a)
#pragma unroll
    for (int r = 0; r < 4; ++r) cc[a][r] = 0.0f;

  __hip_bfloat16* cur = h0;
  __hip_bfloat16* nxt = h1;
  unsigned int* flagsN = flags + n * 32;

  __syncthreads();

  for (int t = 0; t < TLEN; ++t) {
    f32x4 acc[4][2];
#pragma unroll
    for (int tp = 0; tp < 4; ++tp)
#pragma unroll
      for (int nt = 0; nt < 2; ++nt) acc[tp][nt] = (f32x4){0.f, 0.f, 0.f, 0.f};

    const uint4* curU = (const uint4*)cur;
#pragma unroll
    for (int ks = 0; ks < 16; ++ks) {
      bf16x8 hf[2], wf[4];
#pragma unroll
      for (int nt = 0; nt < 2; ++nt)
        hf[nt] = __builtin_bit_cast(bf16x8, curU[hb[nt] + 4 * ks]);
#pragma unroll
      for (int tp = 0; tp < 4; ++tp)
        wf[tp] = __builtin_bit_cast(bf16x8, Wlds[wrow[tp] + ((4 * ks + q) ^ swz)]);
#pragma unroll
      for (int tp = 0; tp < 4; ++tp)
#pragma unroll
        for (int nt = 0; nt < 2; ++nt)
          acc[tp][nt] = __builtin_amdgcn_mfma_f32_16x16x32_bf16(wf[tp], hf[nt], acc[tp][nt], 0, 0, 0);
    }

    // ---- pointwise: lane owns batches bb[0..1] x 4 consecutive cols j0+4q+r ----
    unsigned long long* nxtQ = (unsigned long long*)nxt;
#pragma unroll
    for (int nt = 0; nt < 2; ++nt) {
      float cv = c_in[bb[nt] * 256 + t];
      unsigned int lo = 0, hi = 0;
      float hv3 = 0.f;
#pragma unroll
      for (int r = 0; r < 4; ++r) {
        float gi = acc[0][nt][r] + wih_g[0][r] * cv + bias_g[0][r];
        float gf = acc[1][nt][r] + wih_g[1][r] * cv + bias_g[1][r];
        float gg = acc[2][nt][r] + wih_g[2][r] * cv + bias_g[2][r];
        float go = acc[3][nt][r] + wih_g[3][r] * cv + bias_g[3][r];
        float ncc = sigm(gf) * cc[nt][r] + sigm(gi) * tanh_(gg);
        cc[nt][r] = ncc;
        float hv = sigm(go) * tanh_(ncc);
        unsigned int hb16 = bf16_rne(hv);
        if (r == 0) lo = hb16;
        if (r == 1) lo |= hb16 << 16;
        if (r == 2) hi = hb16;
        if (r == 3) { hi |= hb16 << 16; hv3 = hv; }
      }
      unsigned long long pack = (unsigned long long)lo | ((unsigned long long)hi << 32);
      // write-through (sc1) store: stays out of L2, lands at MALL
      __hip_atomic_store(&nxtQ[(size_t)(n * 128 + bb[nt]) * 128 + jt * 4 + q], pack,
                         __ATOMIC_RELAXED, __HIP_MEMORY_SCOPE_AGENT);
      if (jt == 31 && q == 3)   // col 511 = hidden feature used by the head
        __hip_atomic_store(&ys[t * (NBR * BATCH) + n * BATCH + bb[nt]], hv3,
                           __ATOMIC_RELAXED, __HIP_MEMORY_SCOPE_AGENT);
    }

    if (t == TLEN - 1) break;   // no one consumes h(T); kernel boundary covers ys

    // ---- branch barrier: store-only arrival slots + coalesced poll ----
    __syncthreads();                       // per-wave vmcnt(0): all stores at MALL
    if (tid == 0)
      __hip_atomic_store(&flagsN[jt], (unsigned)(t + 1),
                         __ATOMIC_RELEASE, __HIP_MEMORY_SCOPE_AGENT);
    const unsigned tgt = (unsigned)(t + 1);
    for (;;) {
      unsigned fv = __hip_atomic_load(&flagsN[lane & 31],
                                      __ATOMIC_RELAXED, __HIP_MEMORY_SCOPE_AGENT);
      if (__all((int)(fv >= tgt))) break;
      __builtin_amdgcn_s_sleep(2);
    }
    __builtin_amdgcn_fence(__ATOMIC_ACQUIRE, "agent");  // buffer_inv: h loads see MALL
    __hip_bfloat16* tsw = cur; cur = nxt; nxt = tsw;
  }
}

// out[b,j] = sum_t (sum_n ys[t,n,b] * x[n,b,t]) * Wl[j,t] + bl[j]
__global__ __launch_bounds__(256) void finalize_k(
    const float* __restrict__ ys, const float* __restrict__ x,
    const float* __restrict__ Wl, const float* __restrict__ bl,
    float* __restrict__ out)
{
  int b = blockIdx.x;
  int tid = threadIdx.x;  // = t
  __shared__ float r[256];
  float acc = 0.f;
#pragma unroll
  for (int n = 0; n < NBR; ++n)
    acc += ys[tid * (NBR * BATCH) + n * BATCH + b] * x[(n * BATCH + b) * 256 + tid];
  r[tid] = acc;
  __syncthreads();
  int wv = tid >> 6, ln = tid & 63;
#pragma unroll
  for (int jj = 0; jj < 2; ++jj) {
    int j = wv * 2 + jj;
    float p = 0.f;
#pragma unroll
    for (int t2 = ln; t2 < 256; t2 += 64) p += r[t2] * Wl[j * 256 + t2];
#pragma unroll
    for (int s = 32; s > 0; s >>= 1) p += __shfl_down(p, s, 64);
    if (ln == 0) out[b * NBR + j] = p + bl[j];
  }
}

extern "C" void kernel_launch(void* const* d_in, const int* in_sizes, int n_in,
                              void* d_out, int out_size, void* d_ws, size_t ws_size,
                              hipStream_t stream) {
  const float* x    = (const float*)d_in[0];
  const float* c    = (const float*)d_in[1];
  const float* Wih  = (const float*)d_in[2];
  const float* Whh  = (const float*)d_in[3];
  const float* b_ih = (const float*)d_in[4];
  const float* b_hh = (const float*)d_in[5];
  // d_in[6] = hn0 (zeros; h ping buffer is memset to 0)
  const float* Wl   = (const float*)d_in[7];
  const float* bl   = (const float*)d_in[8];
  float* out = (float*)d_out;

  char* ws = (char*)d_ws;
  const size_t HBYTES = (size_t)NBR * BATCH * HIDN * sizeof(__hip_bfloat16);  // 512KB
  __hip_bfloat16* h0  = (__hip_bfloat16*)(ws);
  __hip_bfloat16* h1  = (__hip_bfloat16*)(ws + HBYTES);
  float* ys           = (float*)(ws + 2 * HBYTES);                            // 1MB
  unsigned int* flags = (unsigned int*)(ws + 2 * HBYTES + (size_t)TLEN * NBR * BATCH * 4);

  // ws is re-poisoned (0xAA) before every timed launch: re-init state every call.
  hipMemsetAsync(h0, 0, HBYTES, stream);              // h(t=0) = 0 (== hn0)
  hipMemsetAsync(flags, 0, NBR * 32 * sizeof(unsigned int), stream);

  lstm_main<<<256, 256, 0, stream>>>(c, Wih, Whh, b_ih, b_hh, h0, h1, ys, flags);
  finalize_k<<<BATCH, 256, 0, stream>>>(ys, x, Wl, bl, out);
}

// Round 3
// 3884.422 us; speedup vs baseline: 2.0123x; 1.3317x over previous
//
#include <hip/hip_runtime.h>
#include <hip/hip_bf16.h>

// 8 independent LSTMs (HID=512, input=1 scalar/step) x T=256, batch 128, then a
// tiny (B,T)->(B,8) projection.
//
// Round 3: zero-cache-maintenance cross-block protocol.
//  Round-2 post-mortem: agent-scope atomics/fences lower to per-block-per-step
//  buffer_wbl2/buffer_inv L2 sweeps -> ~19us/step stall (MfmaUtil 4.3%, compute
//  is only ~1.04us/step). This version emits NO fences in the loop:
//   - h / flag stores: inline-asm global_store sc0 sc1 (write-through, bypass
//     L1+L2, serialize at MALL).
//   - h / flag loads:  inline-asm global_load sc0 sc1 (bypass L1+L2).
//   - ordering: producer = stores -> s_waitcnt vmcnt(0) -> flag store;
//     consumer = poll flag -> loads. vmcnt retires VMEM in order, so staged
//     waits vmcnt(24/16/8/0) pipeline the 32 h-chunk loads 4 deep.
//   - per-WAVE flags (8 branches x 32 blocks x 4 waves): no __syncthreads in
//     the whole step loop (LDS weights are read-only after staging).
//  MFMA structure unchanged from round 2 (validated): A = Whh slice from LDS
//  (16 cols x 4 gate types), B = h, 16x16x32 bf16, acc f32; lane-local i/f/g/o.

#define NBR   8
#define BATCH 128
#define HIDN  512
#define TLEN  256

typedef __attribute__((ext_vector_type(8))) short bf16x8;
typedef __attribute__((ext_vector_type(4))) float f32x4;

__device__ __forceinline__ unsigned short bf16_rne(float f) {
  unsigned int u = __float_as_uint(f);
  u += 0x7FFFu + ((u >> 16) & 1u);
  return (unsigned short)(u >> 16);
}

__device__ __forceinline__ float sigm(float x) {
  return __builtin_amdgcn_rcpf(1.0f + __expf(-x));
}
__device__ __forceinline__ float tanh_(float x) {
  float ax = fabsf(x);
  float e  = __expf(-2.0f * ax);
  float t  = (1.0f - e) * __builtin_amdgcn_rcpf(1.0f + e);
  return copysignf(t, x);
}

// ---- raw system-scope (MALL-coherent) memory ops: never touch L1/L2 state ----
#define HLOAD(d, p, OFF) \
  asm volatile("global_load_dwordx4 %0, %1, off offset:" OFF " sc0 sc1" \
               : "=v"(d) : "v"(p))
#define DLOAD(d, p) \
  asm volatile("global_load_dword %0, %1, off sc0 sc1" : "=v"(d) : "v"(p))
#define QSTORE(p, v) \
  asm volatile("global_store_dwordx2 %0, %1, off sc0 sc1" \
               :: "v"(p), "v"(v) : "memory")
#define DSTORE(p, v) \
  asm volatile("global_store_dword %0, %1, off sc0 sc1" \
               :: "v"(p), "v"(v) : "memory")
#define WAITV(N) asm volatile("s_waitcnt vmcnt(" #N ")" ::: "memory")

// 8 x b128 bypass loads: 4 ks (128 k-elements), 2 batch n-tiles
#define CHUNK_LOAD(BUF, P0, P1) do {          \
    HLOAD((BUF)[0], (P0), "0");               \
    HLOAD((BUF)[1], (P1), "0");               \
    HLOAD((BUF)[2], (P0), "64");              \
    HLOAD((BUF)[3], (P1), "64");              \
    HLOAD((BUF)[4], (P0), "128");             \
    HLOAD((BUF)[5], (P1), "128");             \
    HLOAD((BUF)[6], (P0), "192");             \
    HLOAD((BUF)[7], (P1), "192");             \
  } while (0)

__global__ __launch_bounds__(256, 1) void lstm_main(
    const float* __restrict__ c_in,   // (128,256)
    const float* __restrict__ Wih,    // (8,2048)
    const float* __restrict__ Whh,    // (8,2048,512)
    const float* __restrict__ b_ih,   // (8,2048)
    const float* __restrict__ b_hh,   // (8,2048)
    __hip_bfloat16* __restrict__ h0,  // (8,128,512) bf16 ping (pre-zeroed)
    __hip_bfloat16* __restrict__ h1,  // (8,128,512) bf16 pong
    float* __restrict__ ys,           // (256,8,128)
    unsigned int* __restrict__ flags) // 8 x 128 per-wave slots, pre-zeroed
{
  __shared__ uint4 Wlds[4096];  // 64KB: row = tp*16 + wcol (64 rows) x 64 16B-chunks

  const int tid  = threadIdx.x;
  const int lane = tid & 63;
  const int w    = tid >> 6;          // wave 0..3 -> batches 32w..32w+31
  const int ln15 = lane & 15;
  const int q    = lane >> 4;         // 0..3
  const int n    = blockIdx.x & 7;    // branch
  const int jt   = blockIdx.x >> 3;   // 0..31 hidden-col tile
  const int j0   = jt << 4;
  const int swz  = ln15 & 7;

  // ---- stage Whh slice -> LDS bf16 (once), 16B chunks XOR-swizzled ----
  for (int idx = tid; idx < 4096; idx += 256) {
    int row  = idx >> 6;              // tp*16 + wcol
    int kc   = idx & 63;
    int tp   = row >> 4;
    int wcol = row & 15;
    const float* src = Whh + ((size_t)(n * 2048 + tp * 512 + j0 + wcol) * 512 + kc * 8);
    float4 f0 = *(const float4*)(src);
    float4 f1 = *(const float4*)(src + 4);
    uint4 v;
    v.x = (unsigned)bf16_rne(f0.x) | ((unsigned)bf16_rne(f0.y) << 16);
    v.y = (unsigned)bf16_rne(f0.z) | ((unsigned)bf16_rne(f0.w) << 16);
    v.z = (unsigned)bf16_rne(f1.x) | ((unsigned)bf16_rne(f1.y) << 16);
    v.w = (unsigned)bf16_rne(f1.z) | ((unsigned)bf16_rne(f1.w) << 16);
    Wlds[(row << 6) | (kc ^ (wcol & 7))] = v;
  }

  // per-lane gate constants: type tp, reg r -> hidden col j0 + 4q + r
  float wih_g[4][4], bias_g[4][4];
#pragma unroll
  for (int tp = 0; tp < 4; ++tp)
#pragma unroll
    for (int r = 0; r < 4; ++r) {
      int g = n * 2048 + tp * 512 + j0 + 4 * q + r;
      wih_g[tp][r]  = Wih[g];
      bias_g[tp][r] = b_ih[g] + b_hh[g];
    }

  const int bb0 = w * 32 + ln15;           // batch, n-tile 0
  const int bb1 = bb0 + 16;                // batch, n-tile 1
  // byte offsets into h buffers
  const size_t hoff0 = ((size_t)(n * 128 + bb0) * 64 + q) * 16;
  const size_t hoff1 = ((size_t)(n * 128 + bb1) * 64 + q) * 16;
  const size_t soff0 = ((size_t)(n * 128 + bb0) * 128 + jt * 4 + q) * 8;
  const size_t soff1 = ((size_t)(n * 128 + bb1) * 128 + jt * 4 + q) * 8;

  const int wrow[4] = { (0 * 16 + ln15) << 6, (1 * 16 + ln15) << 6,
                        (2 * 16 + ln15) << 6, (3 * 16 + ln15) << 6 };

  float cc[2][4];
#pragma unroll
  for (int a = 0; a < 2; ++a)
#pragma unroll
    for (int r = 0; r < 4; ++r) cc[a][r] = 0.0f;

  __hip_bfloat16* cur = h0;
  __hip_bfloat16* nxt = h1;
  unsigned int* flagsN = flags + n * 128;
  unsigned int* myflag = flagsN + jt * 4 + w;
  const unsigned int* pf0 = flagsN + lane;        // slots 0..63
  const unsigned int* pf1 = flagsN + 64 + lane;   // slots 64..127

  __syncthreads();   // Wlds ready (the ONLY barrier; loop body has none)

  for (int t = 0; t < TLEN; ++t) {
    f32x4 acc[4][2];
#pragma unroll
    for (int tp = 0; tp < 4; ++tp)
#pragma unroll
      for (int nt = 0; nt < 2; ++nt) acc[tp][nt] = (f32x4){0.f, 0.f, 0.f, 0.f};

    // ---- issue all 32 h-fragment bypass loads (4 chunks x 8), 4-deep pipe ----
    const char* pc0 = (const char*)cur + hoff0;
    const char* pc1 = (const char*)cur + hoff1;
    uint4 hv[4][8];
    CHUNK_LOAD(hv[0], pc0, pc1);
    CHUNK_LOAD(hv[1], pc0 + 256, pc1 + 256);
    CHUNK_LOAD(hv[2], pc0 + 512, pc1 + 512);
    CHUNK_LOAD(hv[3], pc0 + 768, pc1 + 768);

#define MFMA_CHUNK(C) do {                                                    \
    _Pragma("unroll")                                                         \
    for (int k4 = 0; k4 < 4; ++k4) {                                          \
      const int ks = 4 * (C) + k4;                                            \
      bf16x8 wf[4];                                                           \
      _Pragma("unroll")                                                       \
      for (int tp = 0; tp < 4; ++tp)                                          \
        wf[tp] = __builtin_bit_cast(bf16x8, Wlds[wrow[tp] + ((4 * ks + q) ^ swz)]); \
      _Pragma("unroll")                                                       \
      for (int tp = 0; tp < 4; ++tp) {                                        \
        acc[tp][0] = __builtin_amdgcn_mfma_f32_16x16x32_bf16(                 \
            wf[tp], __builtin_bit_cast(bf16x8, hv[C][2 * k4 + 0]), acc[tp][0], 0, 0, 0); \
        acc[tp][1] = __builtin_amdgcn_mfma_f32_16x16x32_bf16(                 \
            wf[tp], __builtin_bit_cast(bf16x8, hv[C][2 * k4 + 1]), acc[tp][1], 0, 0, 0); \
      }                                                                       \
    }                                                                         \
  } while (0)

    WAITV(24); MFMA_CHUNK(0);
    WAITV(16); MFMA_CHUNK(1);
    WAITV(8);  MFMA_CHUNK(2);
    WAITV(0);  MFMA_CHUNK(3);
#undef MFMA_CHUNK

    // ---- pointwise: lane owns batches bb0/bb1 x 4 consecutive cols j0+4q+r ----
    const float cv[2] = { c_in[bb0 * 256 + t], c_in[bb1 * 256 + t] };
#pragma unroll
    for (int nt = 0; nt < 2; ++nt) {
      unsigned int lo = 0, hi = 0;
      float hv3 = 0.f;
#pragma unroll
      for (int r = 0; r < 4; ++r) {
        float gi = acc[0][nt][r] + wih_g[0][r] * cv[nt] + bias_g[0][r];
        float gf = acc[1][nt][r] + wih_g[1][r] * cv[nt] + bias_g[1][r];
        float gg = acc[2][nt][r] + wih_g[2][r] * cv[nt] + bias_g[2][r];
        float go = acc[3][nt][r] + wih_g[3][r] * cv[nt] + bias_g[3][r];
        float ncc = sigm(gf) * cc[nt][r] + sigm(gi) * tanh_(gg);
        cc[nt][r] = ncc;
        float hval = sigm(go) * tanh_(ncc);
        unsigned int hb16 = bf16_rne(hval);
        if (r == 0) lo = hb16;
        if (r == 1) lo |= hb16 << 16;
        if (r == 2) hi = hb16;
        if (r == 3) { hi |= hb16 << 16; hv3 = hval; }
      }
      unsigned long long pack = (unsigned long long)lo | ((unsigned long long)hi << 32);
      const char* ps = (const char*)nxt + (nt ? soff1 : soff0);
      QSTORE(ps, pack);
      if (jt == 31 && q == 3)   // col 511 = the hidden feature the head uses
        ys[t * (NBR * BATCH) + n * BATCH + (nt ? bb1 : bb0)] = hv3;
    }

    if (t == TLEN - 1) break;  // ys flushed at kernel end; nobody reads h(T)

    // ---- per-wave arrival flag + poll (no fences, no __syncthreads) ----
    WAITV(0);                               // h stores acked at MALL
    const unsigned int tgt = (unsigned)(t + 1);
    if (lane == 0) DSTORE(myflag, tgt);
    for (;;) {
      unsigned int f0v, f1v;
      DLOAD(f0v, pf0);
      DLOAD(f1v, pf1);
      WAITV(0);
      if (__all((int)(f0v >= tgt && f1v >= tgt))) break;
      __builtin_amdgcn_s_sleep(4);
    }

    __hip_bfloat16* tsw = cur; cur = nxt; nxt = tsw;
  }
}

// out[b,j] = sum_t (sum_n ys[t,n,b] * x[n,b,t]) * Wl[j,t] + bl[j]
__global__ __launch_bounds__(256) void finalize_k(
    const float* __restrict__ ys, const float* __restrict__ x,
    const float* __restrict__ Wl, const float* __restrict__ bl,
    float* __restrict__ out)
{
  int b = blockIdx.x;
  int tid = threadIdx.x;  // = t
  __shared__ float r[256];
  float acc = 0.f;
#pragma unroll
  for (int n = 0; n < NBR; ++n)
    acc += ys[tid * (NBR * BATCH) + n * BATCH + b] * x[(n * BATCH + b) * 256 + tid];
  r[tid] = acc;
  __syncthreads();
  int wv = tid >> 6, ln = tid & 63;
#pragma unroll
  for (int jj = 0; jj < 2; ++jj) {
    int j = wv * 2 + jj;
    float p = 0.f;
#pragma unroll
    for (int t2 = ln; t2 < 256; t2 += 64) p += r[t2] * Wl[j * 256 + t2];
#pragma unroll
    for (int s = 32; s > 0; s >>= 1) p += __shfl_down(p, s, 64);
    if (ln == 0) out[b * NBR + j] = p + bl[j];
  }
}

extern "C" void kernel_launch(void* const* d_in, const int* in_sizes, int n_in,
                              void* d_out, int out_size, void* d_ws, size_t ws_size,
                              hipStream_t stream) {
  const float* x    = (const float*)d_in[0];
  const float* c    = (const float*)d_in[1];
  const float* Wih  = (const float*)d_in[2];
  const float* Whh  = (const float*)d_in[3];
  const float* b_ih = (const float*)d_in[4];
  const float* b_hh = (const float*)d_in[5];
  // d_in[6] = hn0 (zeros; h ping buffer is memset to 0)
  const float* Wl   = (const float*)d_in[7];
  const float* bl   = (const float*)d_in[8];
  float* out = (float*)d_out;

  char* ws = (char*)d_ws;
  const size_t HBYTES = (size_t)NBR * BATCH * HIDN * sizeof(__hip_bfloat16);  // 512KB
  __hip_bfloat16* h0  = (__hip_bfloat16*)(ws);
  __hip_bfloat16* h1  = (__hip_bfloat16*)(ws + HBYTES);
  float* ys           = (float*)(ws + 2 * HBYTES);                            // 1MB
  unsigned int* flags = (unsigned int*)(ws + 2 * HBYTES + (size_t)TLEN * NBR * BATCH * 4);

  // ws is re-poisoned (0xAA) before every timed launch: re-init state every call.
  hipMemsetAsync(h0, 0, HBYTES, stream);                    // h(t=0) = 0 (== hn0)
  hipMemsetAsync(flags, 0, NBR * 128 * sizeof(unsigned int), stream);

  lstm_main<<<256, 256, 0, stream>>>(c, Wih, Whh, b_ih, b_hh, h0, h1, ys, flags);
  finalize_k<<<BATCH, 256, 0, stream>>>(ys, x, Wl, bl, out);
}